// Round 4
// baseline (580.375 us; speedup 1.0000x reference)
//
#include <hip/hip_runtime.h>
#include <math.h>

#define N_NODES 262144
#define N_EDGES 524288
#define NB      16
#define N_PER   16384
#define KKEEP   8192
#define DIM     128
#define NEG_SLOPE 0.01f
#define CHUNK   2048        // sort chunk size (8 chunks per graph)

// ---- output layout (floats) ----
#define X_OUT   0                     // 131072*128 = 16777216
#define X_EI    16777216              // 2*E = 1048576
#define X_EW    17825792              // E   = 524288
#define X_BATCH 18350080              // B*K = 131072

typedef short s8v __attribute__((ext_vector_type(8)));   // 8 bf16 in 4 VGPRs
typedef float f4v __attribute__((ext_vector_type(4)));   // MFMA accumulator

__device__ __forceinline__ unsigned long long pack_key(float sc, int localIdx) {
    unsigned int u = __float_as_uint(sc);
    u = (u & 0x80000000u) ? ~u : (u | 0x80000000u);   // order-preserving map
    unsigned int inv = ~u;                            // descending score
    return ((unsigned long long)inv << 32) | (unsigned int)localIdx;
}

// RN float->bf16 (round-nearest-even), returns low 16 bits
__device__ __forceinline__ unsigned int f2bf(float x) {
    unsigned int u = __float_as_uint(x);
    return (u + 0x7FFFu + ((u >> 16) & 1u)) >> 16;
}
__device__ __forceinline__ float bf2f(unsigned int h) { return __uint_as_float(h << 16); }

// ================= K1: init =================
__global__ void k_init(float* deg, int* count, int* mapping, const float* pw, float* normPw) {
    int n = blockIdx.x * 256 + threadIdx.x;
    if (n < N_NODES) { deg[n] = 1.0f; count[n] = 0; mapping[n] = -1; }
    if (n == 0) {
        float s = 0.f;
        for (int i = 0; i < DIM; i++) s += pw[i] * pw[i];
        normPw[0] = sqrtf(s);
    }
}

// ===== K_wprep: one-time W[k][n] -> 3-way bf16 Dekker split, transposed [n][k] =====
// Error-free splits: wv = w0 + w1 + w2 + r3, |r3| <= 2^-27 |wv|.
__global__ void k_wprep(const float* Wg, unsigned short* Wt0, unsigned short* Wt1,
                        unsigned short* Wt2) {
    int tid = threadIdx.x;
    for (int j = 0; j < 64; j++) {
        int idx = tid + j * 256;          // 16384 elems
        int k = idx >> 7, n = idx & 127;
        float wv = Wg[k * 128 + n];
        unsigned int h = f2bf(wv);
        float r1 = wv - bf2f(h);          // exact
        unsigned int m = f2bf(r1);
        float r2 = r1 - bf2f(m);          // exact
        unsigned int lo = f2bf(r2);
        Wt0[n * 128 + k] = (unsigned short)h;
        Wt1[n * 128 + k] = (unsigned short)m;
        Wt2[n * 128 + k] = (unsigned short)lo;
    }
}

// ================= K2: degree + in-edge counts =================
__global__ void k_deg(const int* col, const float* w, float* deg, int* count) {
    int e = blockIdx.x * 256 + threadIdx.x;
    if (e >= N_EDGES) return;
    int c = col[e];
    atomicAdd(&deg[c], w[e]);
    atomicAdd(&count[c], 1);
}

// ================= K3a: per-block exclusive scan (2048/block) =================
__global__ void k_scan1(const int* count, int* offs, int* blockSums) {
    __shared__ int s[2048];
    int base = blockIdx.x * 2048;
    int t = threadIdx.x;  // 1024 threads
    s[t]        = count[base + t];
    s[t + 1024] = count[base + t + 1024];
    __syncthreads();
    for (int off = 1; off < 2048; off <<= 1) {
        int a0 = (t >= off)        ? s[t - off]        : 0;
        int a1 = (t + 1024 >= off) ? s[t + 1024 - off] : 0;
        __syncthreads();
        s[t]        += a0;
        s[t + 1024] += a1;
        __syncthreads();
    }
    offs[base + t]        = s[t]        - count[base + t];
    offs[base + t + 1024] = s[t + 1024] - count[base + t + 1024];
    if (t == 0) blockSums[blockIdx.x] = s[2047];
}

// ================= K3b: scan the 128 block sums =================
__global__ void k_scan2(int* blockSums, int* offs) {
    if (threadIdx.x == 0) {
        int run = 0;
        for (int b = 0; b < 128; b++) { int v = blockSums[b]; blockSums[b] = run; run += v; }
        offs[N_NODES] = run;   // == E
    }
}

// ================= K3c: add block offsets, zero cursor, deg->dinv =================
__global__ void k_fixup(int* offs, int* count, float* deg, const int* blockSums) {
    int n = blockIdx.x * 256 + threadIdx.x;
    if (n >= N_NODES) return;
    offs[n] += blockSums[n >> 11];
    count[n] = 0;
    float d = deg[n];
    deg[n] = (d > 0.f) ? (1.0f / sqrtf(d)) : 0.f;   // in-place -> dinv
}

// ================= K4: scatter edges into CSR-by-dst =================
__global__ void k_scatter(const int* row, const int* col, const float* w, const float* dinv,
                          const int* offs, int* cursor, int* ssrc, float* scoef) {
    int e = blockIdx.x * 256 + threadIdx.x;
    if (e >= N_EDGES) return;
    int r = row[e], c = col[e];
    int pos = atomicAdd(&cursor[c], 1);
    int slot = offs[c] + pos;
    ssrc[slot]  = r;
    scoef[slot] = (dinv[r] * w[e]) * dinv[c];
}

// ================= K5: gather-aggregate (A_norm @ x), 32 lanes/node =================
__global__ void k_aggregate(const float* x, const float* dinv, const int* offs,
                            const int* ssrc, const float* scoef, float* agg) {
    int g = blockIdx.x * 256 + threadIdx.x;
    int node = g >> 5, d = g & 31;
    const float4* x4 = (const float4*)x;
    float4 acc = make_float4(0.f, 0.f, 0.f, 0.f);
    int s = offs[node], e = offs[node + 1];
    for (int j = s; j < e; j++) {
        int   src = ssrc[j];
        float cf  = scoef[j];
        float4 v = x4[(size_t)src * 32 + d];
        acc.x += cf * v.x; acc.y += cf * v.y; acc.z += cf * v.z; acc.w += cf * v.w;
    }
    float di = dinv[node];
    float cf = di * di;                 // self-loop: dinv*1*dinv
    float4 v = x4[(size_t)node * 32 + d];
    acc.x += cf * v.x; acc.y += cf * v.y; acc.z += cf * v.z; acc.w += cf * v.w;
    ((float4*)agg)[(size_t)node * 32 + d] = acc;
}

// ======== K6: MFMA GEMM 128x128 tile, 3-way bf16 Dekker split, 8 cross-terms ========
// a = a0+a1+a2 (error-free RN splits, residual 2^-27). 8 MFMA terms per fragment pair:
// hh,hm,mh,mm,hl,lh,ml,lm (ll ~2^-36 dropped) -> total error in fp32-GEMM class (~1e-7),
// which the passing fp32 baseline established is enough to reproduce np's top-K ranking.
// LDS: 6 tiles [128 rows][32 k] bf16 (48 KB), 16B chunk-slot swizzle p = c ^ ((r>>1)&3):
// staging writes and ds_read_b128 frag reads both 2-way per bank-quad (free).
// k-index permutation cancels between A and B frags; C/D map col=l&15, row=(l>>4)*4+r
// (HW-verified; R2's output-0 passed with this plumbing).
__global__ __launch_bounds__(256, 2) void k_gemm(float* hio,
                                                 const unsigned short* Wt0,
                                                 const unsigned short* Wt1,
                                                 const unsigned short* Wt2,
                                                 const float* bias, const float* pw,
                                                 const float* normPw, float* score) {
    __shared__ __align__(16) char smem[49152];
    char* sA0 = smem;                  // [128][32] bf16 = 8KB
    char* sA1 = smem + 8192;
    char* sA2 = smem + 16384;
    char* sW0 = smem + 24576;
    char* sW1 = smem + 32768;
    char* sW2 = smem + 40960;

    int tid = threadIdx.x;
    int l   = tid & 63;
    int w   = tid >> 6;          // wave id 0..3 -> rows w*32..w*32+31
    int l15 = l & 15, l4 = l >> 4;
    int row0 = blockIdx.x * 128;

    f4v acc[2][8];
#pragma unroll
    for (int mt = 0; mt < 2; mt++)
#pragma unroll
        for (int nt = 0; nt < 8; nt++)
#pragma unroll
            for (int r = 0; r < 4; r++) acc[mt][nt][r] = 0.f;

    for (int kh = 0; kh < 4; kh++) {             // 4 chunks of K=32
        if (kh) __syncthreads();                 // frag reads of prev chunk done
        // ---- stage A chunk: 128 rows x 32 k fp32 -> 3x bf16, swizzled ----
#pragma unroll
        for (int i = 0; i < 2; i++) {
            int f = tid + i * 256;               // 0..511
            int r = f >> 2, c = f & 3;
            const float* src = hio + (size_t)(row0 + r) * 128 + kh * 32 + c * 8;
            float4 v0 = *(const float4*)(src);
            float4 v1 = *(const float4*)(src + 4);
            float a[8] = {v0.x, v0.y, v0.z, v0.w, v1.x, v1.y, v1.z, v1.w};
            unsigned int h[8], m[8], lo[8];
#pragma unroll
            for (int j = 0; j < 8; j++) {
                h[j] = f2bf(a[j]);
                float r1 = a[j] - bf2f(h[j]);    // exact
                m[j] = f2bf(r1);
                float r2 = r1 - bf2f(m[j]);      // exact
                lo[j] = f2bf(r2);
            }
            int off = r * 64 + ((c ^ ((r >> 1) & 3)) * 16);
            *(uint4*)(sA0 + off) = make_uint4(h[0] | (h[1] << 16), h[2] | (h[3] << 16),
                                              h[4] | (h[5] << 16), h[6] | (h[7] << 16));
            *(uint4*)(sA1 + off) = make_uint4(m[0] | (m[1] << 16), m[2] | (m[3] << 16),
                                              m[4] | (m[5] << 16), m[6] | (m[7] << 16));
            *(uint4*)(sA2 + off) = make_uint4(lo[0] | (lo[1] << 16), lo[2] | (lo[3] << 16),
                                              lo[4] | (lo[5] << 16), lo[6] | (lo[7] << 16));
        }
        // ---- stage W chunk: [128 n][32 k] bf16 x3 from pre-split global, swizzled ----
#pragma unroll
        for (int i = 0; i < 2; i++) {
            int f = tid + i * 256;
            int n = f >> 2, c = f & 3;
            size_t gb = (size_t)n * 256 + kh * 64 + c * 16;   // bytes ([n][128k] bf16)
            int off = n * 64 + ((c ^ ((n >> 1) & 3)) * 16);
            *(uint4*)(sW0 + off) = *(const uint4*)((const char*)Wt0 + gb);
            *(uint4*)(sW1 + off) = *(const uint4*)((const char*)Wt1 + gb);
            *(uint4*)(sW2 + off) = *(const uint4*)((const char*)Wt2 + gb);
        }
        __syncthreads();

        // ---- fragments + MFMA ----
        s8v ah[2], am[2], al[2];
#pragma unroll
        for (int mt = 0; mt < 2; mt++) {
            int r = w * 32 + mt * 16 + l15;
            int off = r * 64 + ((l4 ^ ((r >> 1) & 3)) * 16);
            ah[mt] = *(const s8v*)(sA0 + off);
            am[mt] = *(const s8v*)(sA1 + off);
            al[mt] = *(const s8v*)(sA2 + off);
        }
#pragma unroll
        for (int nt = 0; nt < 8; nt++) {
            int rn = nt * 16 + l15;
            int offb = rn * 64 + ((l4 ^ ((rn >> 1) & 3)) * 16);
            s8v b0 = *(const s8v*)(sW0 + offb);
            s8v b1 = *(const s8v*)(sW1 + offb);
            s8v b2 = *(const s8v*)(sW2 + offb);
#pragma unroll
            for (int mt = 0; mt < 2; mt++) {
                acc[mt][nt] = __builtin_amdgcn_mfma_f32_16x16x32_bf16(ah[mt], b0, acc[mt][nt], 0, 0, 0);
                acc[mt][nt] = __builtin_amdgcn_mfma_f32_16x16x32_bf16(ah[mt], b1, acc[mt][nt], 0, 0, 0);
                acc[mt][nt] = __builtin_amdgcn_mfma_f32_16x16x32_bf16(am[mt], b0, acc[mt][nt], 0, 0, 0);
                acc[mt][nt] = __builtin_amdgcn_mfma_f32_16x16x32_bf16(am[mt], b1, acc[mt][nt], 0, 0, 0);
                acc[mt][nt] = __builtin_amdgcn_mfma_f32_16x16x32_bf16(ah[mt], b2, acc[mt][nt], 0, 0, 0);
                acc[mt][nt] = __builtin_amdgcn_mfma_f32_16x16x32_bf16(al[mt], b0, acc[mt][nt], 0, 0, 0);
                acc[mt][nt] = __builtin_amdgcn_mfma_f32_16x16x32_bf16(am[mt], b2, acc[mt][nt], 0, 0, 0);
                acc[mt][nt] = __builtin_amdgcn_mfma_f32_16x16x32_bf16(al[mt], b1, acc[mt][nt], 0, 0, 0);
            }
        }
    }

    // ---- epilogue: bias + leaky + h write (in-place) + score ----
    float bv[8], pv[8];
#pragma unroll
    for (int nt = 0; nt < 8; nt++) {
        bv[nt] = bias[nt * 16 + l15];
        pv[nt] = pw[nt * 16 + l15];
    }
    float nrm = normPw[0];
    float sp[2][4];
#pragma unroll
    for (int mt = 0; mt < 2; mt++)
#pragma unroll
        for (int r = 0; r < 4; r++) sp[mt][r] = 0.f;

#pragma unroll
    for (int mt = 0; mt < 2; mt++) {
#pragma unroll
        for (int r = 0; r < 4; r++) {
            int row = row0 + w * 32 + mt * 16 + l4 * 4 + r;
#pragma unroll
            for (int nt = 0; nt < 8; nt++) {
                float v = acc[mt][nt][r] + bv[nt];
                v = (v >= 0.f) ? v : NEG_SLOPE * v;
                hio[(size_t)row * 128 + nt * 16 + l15] = v;
                sp[mt][r] += v * pv[nt];
            }
        }
    }
#pragma unroll
    for (int m = 1; m < 16; m <<= 1) {
#pragma unroll
        for (int mt = 0; mt < 2; mt++)
#pragma unroll
            for (int r = 0; r < 4; r++) sp[mt][r] += __shfl_xor(sp[mt][r], m, 64);
    }
    if (l15 == 0) {
#pragma unroll
        for (int mt = 0; mt < 2; mt++)
#pragma unroll
            for (int r = 0; r < 4; r++) {
                int row = row0 + w * 32 + mt * 16 + l4 * 4 + r;
                score[row] = tanhf(sp[mt][r] / nrm);
            }
    }
}

// ================= K7: per-chunk LDS bitonic sort (128 blocks x 2048 keys) =================
__global__ void __launch_bounds__(1024) k_sortchunks(const float* score,
                                                     unsigned long long* keys) {
    __shared__ unsigned long long a[CHUNK];     // 16 KB
    int base = blockIdx.x * CHUNK;              // chunk-aligned within a graph
    int t = threadIdx.x;
#pragma unroll
    for (int i = 0; i < CHUNK / 1024; i++) {
        int p = t + i * 1024;
        int node = base + p;
        a[p] = pack_key(score[node], node & (N_PER - 1));
    }
    __syncthreads();
    for (int k = 2; k <= CHUNK; k <<= 1) {
        for (int j = k >> 1; j > 0; j >>= 1) {
#pragma unroll
            for (int q = 0; q < CHUNK / 2048; q++) {
                int tt = t + q * 1024;
                int i = ((tt & ~(j - 1)) << 1) | (tt & (j - 1));
                int l = i | j;
                bool asc = ((i & k) == 0);
                unsigned long long x = a[i], y = a[l];
                if ((x > y) == asc) { a[i] = y; a[l] = x; }
            }
            __syncthreads();
        }
    }
#pragma unroll
    for (int i = 0; i < CHUNK / 1024; i++) {
        int p = t + i * 1024;
        keys[base + p] = a[p];
    }
}

// ================= K8: rank via binary search over sorted chunks, fused extract =================
__global__ void k_rank(const float* score, const unsigned long long* keys,
                       int* perm, int* mapping, float* out) {
    int n = blockIdx.x * 256 + threadIdx.x;
    if (n >= N_NODES) return;
    int g = n >> 14;
    unsigned long long key = pack_key(score[n], n & (N_PER - 1));
    const unsigned long long* gb = keys + ((size_t)g << 14);
    int r = 0;
#pragma unroll
    for (int c = 0; c < N_PER / CHUNK; c++) {
        const unsigned long long* ch = gb + c * CHUNK;
        int lo = 0, hi = CHUNK;
        while (lo < hi) {
            int mid = (lo + hi) >> 1;
            if (ch[mid] < key) lo = mid + 1; else hi = mid;
        }
        r += lo;
    }
    if (r < KKEEP) {
        int i = (g << 13) + r;
        perm[i] = n;
        mapping[n] = i;
        out[X_BATCH + i] = (float)g;
    }
}

// ================= K10: gate kept rows =================
__global__ void k_gate(const float* h, const float* score, const int* perm, float* out) {
    int g = blockIdx.x * 256 + threadIdx.x;
    int i = g >> 5, d = g & 31;
    int node = perm[i];
    float sc = score[node];
    float4 v = ((const float4*)h)[(size_t)node * 32 + d];
    v.x *= sc; v.y *= sc; v.z *= sc; v.w *= sc;
    ((float4*)(out + X_OUT))[(size_t)i * 32 + d] = v;
}

// ================= K11: relabel edges =================
__global__ void k_edges(const int* row, const int* col, const float* w,
                        const int* mapping, float* out) {
    int e = blockIdx.x * 256 + threadIdx.x;
    if (e >= N_EDGES) return;
    int mr = mapping[row[e]], mc = mapping[col[e]];
    bool valid = (mr >= 0) && (mc >= 0);
    out[X_EI + e]           = valid ? (float)mr : 0.f;
    out[X_EI + N_EDGES + e] = valid ? (float)mc : 0.f;
    out[X_EW + e]           = valid ? w[e] : 0.f;
}

extern "C" void kernel_launch(void* const* d_in, const int* in_sizes, int n_in,
                              void* d_out, int out_size, void* d_ws, size_t ws_size,
                              hipStream_t stream) {
    const float* x     = (const float*)d_in[0];
    const int*   ei    = (const int*)d_in[1];
    const float* ew    = (const float*)d_in[2];
    const float* Wc    = (const float*)d_in[4];
    const float* bias  = (const float*)d_in[5];
    const float* pw    = (const float*)d_in[6];
    float* out = (float*)d_out;

    const int* rowp = ei;
    const int* colp = ei + N_EDGES;

    char* wsb = (char*)d_ws;
    float* agg     = (float*)(wsb);                          // N*128*4 = 134217728
    float* dinv    = (float*)(wsb + 134217728);              // N*4 (deg, then dinv)
    int*   count   = (int*)  (wsb + 135266304);              // N*4 (counts, then cursor)
    int*   offs    = (int*)  (wsb + 136314880);              // (N+1)*4 padded
    int*   ssrc    = (int*)  (wsb + 137363712);              // E*4
    float* scoef   = (float*)(wsb + 139460864);              // E*4
    float* score   = (float*)(wsb + 141557760);              // N*4
    unsigned long long* keys = (unsigned long long*)(wsb + 142606336);  // N*8
    int*   perm    = (int*)  (wsb + 144703488);              // B*K*4
    int*   mapping = (int*)  (wsb + 145227776);              // N*4
    int*   blockSums = (int*)(wsb + 146276352);              // 128*4 padded
    float* normPw  = (float*)(wsb + 146277376);              // 4
    unsigned short* Wt0 = (unsigned short*)(wsb + 146278400);  // 128*128*2 = 32768
    unsigned short* Wt1 = (unsigned short*)(wsb + 146311168);  // 32768
    unsigned short* Wt2 = (unsigned short*)(wsb + 146343936);  // 32768

    k_init   <<<N_NODES / 256, 256, 0, stream>>>(dinv, count, mapping, pw, normPw);
    k_wprep  <<<1, 256, 0, stream>>>(Wc, Wt0, Wt1, Wt2);
    k_deg    <<<N_EDGES / 256, 256, 0, stream>>>(colp, ew, dinv, count);
    k_scan1  <<<128, 1024, 0, stream>>>(count, offs, blockSums);
    k_scan2  <<<1, 64, 0, stream>>>(blockSums, offs);
    k_fixup  <<<N_NODES / 256, 256, 0, stream>>>(offs, count, dinv, blockSums);
    k_scatter<<<N_EDGES / 256, 256, 0, stream>>>(rowp, colp, ew, dinv, offs, count, ssrc, scoef);
    k_aggregate<<<(N_NODES * 32) / 256, 256, 0, stream>>>(x, dinv, offs, ssrc, scoef, agg);
    k_gemm   <<<N_NODES / 128, 256, 0, stream>>>(agg, Wt0, Wt1, Wt2, bias, pw, normPw, score);
    k_sortchunks<<<N_NODES / CHUNK, 1024, 0, stream>>>(score, keys);
    k_rank   <<<N_NODES / 256, 256, 0, stream>>>(score, keys, perm, mapping, out);
    k_gate   <<<(NB * KKEEP * 32) / 256, 256, 0, stream>>>(agg, score, perm, out);
    k_edges  <<<N_EDGES / 256, 256, 0, stream>>>(rowp, colp, ew, mapping, out);
}

// Round 5
// 495.205 us; speedup vs baseline: 1.1720x; 1.1720x over previous
//
#include <hip/hip_runtime.h>
#include <math.h>

#define N_NODES 262144
#define N_EDGES 524288
#define NB      16
#define N_PER   16384
#define KKEEP   8192
#define DIM     128
#define NEG_SLOPE 0.01f
#define CHUNK   2048        // sort chunk size (8 chunks per graph)

// ---- output layout (floats) ----
#define X_OUT   0                     // 131072*128 = 16777216
#define X_EI    16777216              // 2*E = 1048576
#define X_EW    17825792              // E   = 524288
#define X_BATCH 18350080              // B*K = 131072

typedef short s8v __attribute__((ext_vector_type(8)));   // 8 bf16 in 4 VGPRs
typedef float f4v __attribute__((ext_vector_type(4)));   // MFMA accumulator

__device__ __forceinline__ unsigned long long pack_key(float sc, int localIdx) {
    unsigned int u = __float_as_uint(sc);
    u = (u & 0x80000000u) ? ~u : (u | 0x80000000u);   // order-preserving map
    unsigned int inv = ~u;                            // descending score
    return ((unsigned long long)inv << 32) | (unsigned int)localIdx;
}

// RN float->bf16 (round-nearest-even), returns low 16 bits
__device__ __forceinline__ unsigned int f2bf(float x) {
    unsigned int u = __float_as_uint(x);
    return (u + 0x7FFFu + ((u >> 16) & 1u)) >> 16;
}
__device__ __forceinline__ float bf2f(unsigned int h) { return __uint_as_float(h << 16); }

// ================= K1: init =================
__global__ void k_init(float* deg, int* count, int* mapping, const float* pw, float* normPw) {
    int n = blockIdx.x * 256 + threadIdx.x;
    if (n < N_NODES) { deg[n] = 1.0f; count[n] = 0; mapping[n] = -1; }
    if (n == 0) {
        float s = 0.f;
        for (int i = 0; i < DIM; i++) s += pw[i] * pw[i];
        normPw[0] = sqrtf(s);
    }
}

// ===== K_wprep: one-time W[k][n] -> 3-way bf16 Dekker split, transposed [n][k] =====
// Error-free splits: wv = w0 + w1 + w2 + r3, |r3| <= 2^-27 |wv|.
__global__ void k_wprep(const float* Wg, unsigned short* Wt0, unsigned short* Wt1,
                        unsigned short* Wt2) {
    int idx = blockIdx.x * 256 + threadIdx.x;     // 16384 elems over 64 blocks
    if (idx >= DIM * DIM) return;
    int k = idx >> 7, n = idx & 127;
    float wv = Wg[k * 128 + n];
    unsigned int h = f2bf(wv);
    float r1 = wv - bf2f(h);          // exact
    unsigned int m = f2bf(r1);
    float r2 = r1 - bf2f(m);          // exact
    unsigned int lo = f2bf(r2);
    Wt0[n * 128 + k] = (unsigned short)h;
    Wt1[n * 128 + k] = (unsigned short)m;
    Wt2[n * 128 + k] = (unsigned short)lo;
}

// ================= K2: degree + in-edge counts =================
__global__ void k_deg(const int* col, const float* w, float* deg, int* count) {
    int e = blockIdx.x * 256 + threadIdx.x;
    if (e >= N_EDGES) return;
    int c = col[e];
    atomicAdd(&deg[c], w[e]);
    atomicAdd(&count[c], 1);
}

// ================= K3a: per-block exclusive scan (2048/block) =================
__global__ void k_scan1(const int* count, int* offs, int* blockSums) {
    __shared__ int s[2048];
    int base = blockIdx.x * 2048;
    int t = threadIdx.x;  // 1024 threads
    s[t]        = count[base + t];
    s[t + 1024] = count[base + t + 1024];
    __syncthreads();
    for (int off = 1; off < 2048; off <<= 1) {
        int a0 = (t >= off)        ? s[t - off]        : 0;
        int a1 = (t + 1024 >= off) ? s[t + 1024 - off] : 0;
        __syncthreads();
        s[t]        += a0;
        s[t + 1024] += a1;
        __syncthreads();
    }
    offs[base + t]        = s[t]        - count[base + t];
    offs[base + t + 1024] = s[t + 1024] - count[base + t + 1024];
    if (t == 0) blockSums[blockIdx.x] = s[2047];
}

// ================= K3b: scan the 128 block sums =================
__global__ void k_scan2(int* blockSums, int* offs) {
    if (threadIdx.x == 0) {
        int run = 0;
        for (int b = 0; b < 128; b++) { int v = blockSums[b]; blockSums[b] = run; run += v; }
        offs[N_NODES] = run;   // == E
    }
}

// ================= K3c: add block offsets, zero cursor, deg->dinv =================
__global__ void k_fixup(int* offs, int* count, float* deg, const int* blockSums) {
    int n = blockIdx.x * 256 + threadIdx.x;
    if (n >= N_NODES) return;
    offs[n] += blockSums[n >> 11];
    count[n] = 0;
    float d = deg[n];
    deg[n] = (d > 0.f) ? (1.0f / sqrtf(d)) : 0.f;   // in-place -> dinv
}

// ================= K4: scatter edges into CSR-by-dst =================
__global__ void k_scatter(const int* row, const int* col, const float* w, const float* dinv,
                          const int* offs, int* cursor, int* ssrc, float* scoef) {
    int e = blockIdx.x * 256 + threadIdx.x;
    if (e >= N_EDGES) return;
    int r = row[e], c = col[e];
    int pos = atomicAdd(&cursor[c], 1);
    int slot = offs[c] + pos;
    ssrc[slot]  = r;
    scoef[slot] = (dinv[r] * w[e]) * dinv[c];
}

// ======== K5: gather-aggregate (A_norm @ x), 32 lanes/node, MLP-batched ========
// R4 profile: 117.8us, 2.7TB/s, VALU 10% -> latency-bound (MLP=1 dependent chain
// ssrc[j] -> x[src] per edge). Fix: batch 4/2 edges (independent ssrc/scoef scalar
// loads, then all x-row gathers issued back-to-back) + hoist self-row load to top.
// Accumulation ORDER unchanged (j, j+1, ... then self) -> bitwise-identical result.
__global__ void k_aggregate(const float* x, const float* dinv, const int* offs,
                            const int* ssrc, const float* scoef, float* agg) {
    int g = blockIdx.x * 256 + threadIdx.x;
    int node = g >> 5, d = g & 31;
    const float4* x4 = (const float4*)x;
    int s = offs[node], e = offs[node + 1];

    float4 vs = x4[(size_t)node * 32 + d];    // self row: in flight during edge loop
    float di = dinv[node];

    float4 acc = make_float4(0.f, 0.f, 0.f, 0.f);
    int j = s;
    while (j + 4 <= e) {
        int   s0 = ssrc[j],  s1 = ssrc[j + 1],  s2 = ssrc[j + 2],  s3 = ssrc[j + 3];
        float c0 = scoef[j], c1 = scoef[j + 1], c2 = scoef[j + 2], c3 = scoef[j + 3];
        float4 va = x4[(size_t)s0 * 32 + d];
        float4 vb = x4[(size_t)s1 * 32 + d];
        float4 vc = x4[(size_t)s2 * 32 + d];
        float4 vd = x4[(size_t)s3 * 32 + d];
        acc.x += c0 * va.x; acc.y += c0 * va.y; acc.z += c0 * va.z; acc.w += c0 * va.w;
        acc.x += c1 * vb.x; acc.y += c1 * vb.y; acc.z += c1 * vb.z; acc.w += c1 * vb.w;
        acc.x += c2 * vc.x; acc.y += c2 * vc.y; acc.z += c2 * vc.z; acc.w += c2 * vc.w;
        acc.x += c3 * vd.x; acc.y += c3 * vd.y; acc.z += c3 * vd.z; acc.w += c3 * vd.w;
        j += 4;
    }
    if (j + 2 <= e) {
        int   s0 = ssrc[j],  s1 = ssrc[j + 1];
        float c0 = scoef[j], c1 = scoef[j + 1];
        float4 va = x4[(size_t)s0 * 32 + d];
        float4 vb = x4[(size_t)s1 * 32 + d];
        acc.x += c0 * va.x; acc.y += c0 * va.y; acc.z += c0 * va.z; acc.w += c0 * va.w;
        acc.x += c1 * vb.x; acc.y += c1 * vb.y; acc.z += c1 * vb.z; acc.w += c1 * vb.w;
        j += 2;
    }
    if (j < e) {
        int   s0 = ssrc[j];
        float c0 = scoef[j];
        float4 va = x4[(size_t)s0 * 32 + d];
        acc.x += c0 * va.x; acc.y += c0 * va.y; acc.z += c0 * va.z; acc.w += c0 * va.w;
    }
    float cf = di * di;                 // self-loop: dinv*1*dinv (added last, as before)
    acc.x += cf * vs.x; acc.y += cf * vs.y; acc.z += cf * vs.z; acc.w += cf * vs.w;
    ((float4*)agg)[(size_t)node * 32 + d] = acc;
}

// ======== K6: MFMA GEMM 128x128 tile, 3-way bf16 Dekker split, 8 cross-terms ========
// a = a0+a1+a2 (error-free RN splits, residual 2^-27). 8 MFMA terms per fragment pair:
// hh,hm,mh,mm,hl,lh,ml,lm (ll ~2^-36 dropped) -> total error in fp32-GEMM class (~1e-7).
// R4: passed with absmax == fp32 baseline (2.235931) -> ranking reproduced.
__global__ __launch_bounds__(256, 2) void k_gemm(float* hio,
                                                 const unsigned short* Wt0,
                                                 const unsigned short* Wt1,
                                                 const unsigned short* Wt2,
                                                 const float* bias, const float* pw,
                                                 const float* normPw, float* score) {
    __shared__ __align__(16) char smem[49152];
    char* sA0 = smem;                  // [128][32] bf16 = 8KB
    char* sA1 = smem + 8192;
    char* sA2 = smem + 16384;
    char* sW0 = smem + 24576;
    char* sW1 = smem + 32768;
    char* sW2 = smem + 40960;

    int tid = threadIdx.x;
    int l   = tid & 63;
    int w   = tid >> 6;          // wave id 0..3 -> rows w*32..w*32+31
    int l15 = l & 15, l4 = l >> 4;
    int row0 = blockIdx.x * 128;

    f4v acc[2][8];
#pragma unroll
    for (int mt = 0; mt < 2; mt++)
#pragma unroll
        for (int nt = 0; nt < 8; nt++)
#pragma unroll
            for (int r = 0; r < 4; r++) acc[mt][nt][r] = 0.f;

    for (int kh = 0; kh < 4; kh++) {             // 4 chunks of K=32
        if (kh) __syncthreads();                 // frag reads of prev chunk done
        // ---- stage A chunk: 128 rows x 32 k fp32 -> 3x bf16, swizzled ----
#pragma unroll
        for (int i = 0; i < 2; i++) {
            int f = tid + i * 256;               // 0..511
            int r = f >> 2, c = f & 3;
            const float* src = hio + (size_t)(row0 + r) * 128 + kh * 32 + c * 8;
            float4 v0 = *(const float4*)(src);
            float4 v1 = *(const float4*)(src + 4);
            float a[8] = {v0.x, v0.y, v0.z, v0.w, v1.x, v1.y, v1.z, v1.w};
            unsigned int h[8], m[8], lo[8];
#pragma unroll
            for (int j = 0; j < 8; j++) {
                h[j] = f2bf(a[j]);
                float r1 = a[j] - bf2f(h[j]);    // exact
                m[j] = f2bf(r1);
                float r2 = r1 - bf2f(m[j]);      // exact
                lo[j] = f2bf(r2);
            }
            int off = r * 64 + ((c ^ ((r >> 1) & 3)) * 16);
            *(uint4*)(sA0 + off) = make_uint4(h[0] | (h[1] << 16), h[2] | (h[3] << 16),
                                              h[4] | (h[5] << 16), h[6] | (h[7] << 16));
            *(uint4*)(sA1 + off) = make_uint4(m[0] | (m[1] << 16), m[2] | (m[3] << 16),
                                              m[4] | (m[5] << 16), m[6] | (m[7] << 16));
            *(uint4*)(sA2 + off) = make_uint4(lo[0] | (lo[1] << 16), lo[2] | (lo[3] << 16),
                                              lo[4] | (lo[5] << 16), lo[6] | (lo[7] << 16));
        }
        // ---- stage W chunk: [128 n][32 k] bf16 x3 from pre-split global, swizzled ----
#pragma unroll
        for (int i = 0; i < 2; i++) {
            int f = tid + i * 256;
            int n = f >> 2, c = f & 3;
            size_t gb = (size_t)n * 256 + kh * 64 + c * 16;   // bytes ([n][128k] bf16)
            int off = n * 64 + ((c ^ ((n >> 1) & 3)) * 16);
            *(uint4*)(sW0 + off) = *(const uint4*)((const char*)Wt0 + gb);
            *(uint4*)(sW1 + off) = *(const uint4*)((const char*)Wt1 + gb);
            *(uint4*)(sW2 + off) = *(const uint4*)((const char*)Wt2 + gb);
        }
        __syncthreads();

        // ---- fragments + MFMA ----
        s8v ah[2], am[2], al[2];
#pragma unroll
        for (int mt = 0; mt < 2; mt++) {
            int r = w * 32 + mt * 16 + l15;
            int off = r * 64 + ((l4 ^ ((r >> 1) & 3)) * 16);
            ah[mt] = *(const s8v*)(sA0 + off);
            am[mt] = *(const s8v*)(sA1 + off);
            al[mt] = *(const s8v*)(sA2 + off);
        }
#pragma unroll
        for (int nt = 0; nt < 8; nt++) {
            int rn = nt * 16 + l15;
            int offb = rn * 64 + ((l4 ^ ((rn >> 1) & 3)) * 16);
            s8v b0 = *(const s8v*)(sW0 + offb);
            s8v b1 = *(const s8v*)(sW1 + offb);
            s8v b2 = *(const s8v*)(sW2 + offb);
#pragma unroll
            for (int mt = 0; mt < 2; mt++) {
                acc[mt][nt] = __builtin_amdgcn_mfma_f32_16x16x32_bf16(ah[mt], b0, acc[mt][nt], 0, 0, 0);
                acc[mt][nt] = __builtin_amdgcn_mfma_f32_16x16x32_bf16(ah[mt], b1, acc[mt][nt], 0, 0, 0);
                acc[mt][nt] = __builtin_amdgcn_mfma_f32_16x16x32_bf16(am[mt], b0, acc[mt][nt], 0, 0, 0);
                acc[mt][nt] = __builtin_amdgcn_mfma_f32_16x16x32_bf16(am[mt], b1, acc[mt][nt], 0, 0, 0);
                acc[mt][nt] = __builtin_amdgcn_mfma_f32_16x16x32_bf16(ah[mt], b2, acc[mt][nt], 0, 0, 0);
                acc[mt][nt] = __builtin_amdgcn_mfma_f32_16x16x32_bf16(al[mt], b0, acc[mt][nt], 0, 0, 0);
                acc[mt][nt] = __builtin_amdgcn_mfma_f32_16x16x32_bf16(am[mt], b2, acc[mt][nt], 0, 0, 0);
                acc[mt][nt] = __builtin_amdgcn_mfma_f32_16x16x32_bf16(al[mt], b1, acc[mt][nt], 0, 0, 0);
            }
        }
    }

    // ---- epilogue: bias + leaky + h write (in-place) + score ----
    float bv[8], pv[8];
#pragma unroll
    for (int nt = 0; nt < 8; nt++) {
        bv[nt] = bias[nt * 16 + l15];
        pv[nt] = pw[nt * 16 + l15];
    }
    float nrm = normPw[0];
    float sp[2][4];
#pragma unroll
    for (int mt = 0; mt < 2; mt++)
#pragma unroll
        for (int r = 0; r < 4; r++) sp[mt][r] = 0.f;

#pragma unroll
    for (int mt = 0; mt < 2; mt++) {
#pragma unroll
        for (int r = 0; r < 4; r++) {
            int row = row0 + w * 32 + mt * 16 + l4 * 4 + r;
#pragma unroll
            for (int nt = 0; nt < 8; nt++) {
                float v = acc[mt][nt][r] + bv[nt];
                v = (v >= 0.f) ? v : NEG_SLOPE * v;
                hio[(size_t)row * 128 + nt * 16 + l15] = v;
                sp[mt][r] += v * pv[nt];
            }
        }
    }
#pragma unroll
    for (int m = 1; m < 16; m <<= 1) {
#pragma unroll
        for (int mt = 0; mt < 2; mt++)
#pragma unroll
            for (int r = 0; r < 4; r++) sp[mt][r] += __shfl_xor(sp[mt][r], m, 64);
    }
    if (l15 == 0) {
#pragma unroll
        for (int mt = 0; mt < 2; mt++)
#pragma unroll
            for (int r = 0; r < 4; r++) {
                int row = row0 + w * 32 + mt * 16 + l4 * 4 + r;
                score[row] = tanhf(sp[mt][r] / nrm);
            }
    }
}

// ================= K7: per-chunk LDS bitonic sort (128 blocks x 2048 keys) =================
__global__ void __launch_bounds__(1024) k_sortchunks(const float* score,
                                                     unsigned long long* keys) {
    __shared__ unsigned long long a[CHUNK];     // 16 KB
    int base = blockIdx.x * CHUNK;              // chunk-aligned within a graph
    int t = threadIdx.x;
#pragma unroll
    for (int i = 0; i < CHUNK / 1024; i++) {
        int p = t + i * 1024;
        int node = base + p;
        a[p] = pack_key(score[node], node & (N_PER - 1));
    }
    __syncthreads();
    for (int k = 2; k <= CHUNK; k <<= 1) {
        for (int j = k >> 1; j > 0; j >>= 1) {
#pragma unroll
            for (int q = 0; q < CHUNK / 2048; q++) {
                int tt = t + q * 1024;
                int i = ((tt & ~(j - 1)) << 1) | (tt & (j - 1));
                int l = i | j;
                bool asc = ((i & k) == 0);
                unsigned long long x = a[i], y = a[l];
                if ((x > y) == asc) { a[i] = y; a[l] = x; }
            }
            __syncthreads();
        }
    }
#pragma unroll
    for (int i = 0; i < CHUNK / 1024; i++) {
        int p = t + i * 1024;
        keys[base + p] = a[p];
    }
}

// ================= K8: rank via binary search over sorted chunks, fused extract =================
__global__ void k_rank(const float* score, const unsigned long long* keys,
                       int* perm, int* mapping, float* out) {
    int n = blockIdx.x * 256 + threadIdx.x;
    if (n >= N_NODES) return;
    int g = n >> 14;
    unsigned long long key = pack_key(score[n], n & (N_PER - 1));
    const unsigned long long* gb = keys + ((size_t)g << 14);
    int r = 0;
#pragma unroll
    for (int c = 0; c < N_PER / CHUNK; c++) {
        const unsigned long long* ch = gb + c * CHUNK;
        int lo = 0, hi = CHUNK;
        while (lo < hi) {
            int mid = (lo + hi) >> 1;
            if (ch[mid] < key) lo = mid + 1; else hi = mid;
        }
        r += lo;
    }
    if (r < KKEEP) {
        int i = (g << 13) + r;
        perm[i] = n;
        mapping[n] = i;
        out[X_BATCH + i] = (float)g;
    }
}

// ================= K10: gate kept rows =================
__global__ void k_gate(const float* h, const float* score, const int* perm, float* out) {
    int g = blockIdx.x * 256 + threadIdx.x;
    int i = g >> 5, d = g & 31;
    int node = perm[i];
    float sc = score[node];
    float4 v = ((const float4*)h)[(size_t)node * 32 + d];
    v.x *= sc; v.y *= sc; v.z *= sc; v.w *= sc;
    ((float4*)(out + X_OUT))[(size_t)i * 32 + d] = v;
}

// ================= K11: relabel edges =================
__global__ void k_edges(const int* row, const int* col, const float* w,
                        const int* mapping, float* out) {
    int e = blockIdx.x * 256 + threadIdx.x;
    if (e >= N_EDGES) return;
    int mr = mapping[row[e]], mc = mapping[col[e]];
    bool valid = (mr >= 0) && (mc >= 0);
    out[X_EI + e]           = valid ? (float)mr : 0.f;
    out[X_EI + N_EDGES + e] = valid ? (float)mc : 0.f;
    out[X_EW + e]           = valid ? w[e] : 0.f;
}

extern "C" void kernel_launch(void* const* d_in, const int* in_sizes, int n_in,
                              void* d_out, int out_size, void* d_ws, size_t ws_size,
                              hipStream_t stream) {
    const float* x     = (const float*)d_in[0];
    const int*   ei    = (const int*)d_in[1];
    const float* ew    = (const float*)d_in[2];
    const float* Wc    = (const float*)d_in[4];
    const float* bias  = (const float*)d_in[5];
    const float* pw    = (const float*)d_in[6];
    float* out = (float*)d_out;

    const int* rowp = ei;
    const int* colp = ei + N_EDGES;

    char* wsb = (char*)d_ws;
    float* agg     = (float*)(wsb);                          // N*128*4 = 134217728
    float* dinv    = (float*)(wsb + 134217728);              // N*4 (deg, then dinv)
    int*   count   = (int*)  (wsb + 135266304);              // N*4 (counts, then cursor)
    int*   offs    = (int*)  (wsb + 136314880);              // (N+1)*4 padded
    int*   ssrc    = (int*)  (wsb + 137363712);              // E*4
    float* scoef   = (float*)(wsb + 139460864);              // E*4
    float* score   = (float*)(wsb + 141557760);              // N*4
    unsigned long long* keys = (unsigned long long*)(wsb + 142606336);  // N*8
    int*   perm    = (int*)  (wsb + 144703488);              // B*K*4
    int*   mapping = (int*)  (wsb + 145227776);              // N*4
    int*   blockSums = (int*)(wsb + 146276352);              // 128*4 padded
    float* normPw  = (float*)(wsb + 146277376);              // 4
    unsigned short* Wt0 = (unsigned short*)(wsb + 146278400);  // 128*128*2 = 32768
    unsigned short* Wt1 = (unsigned short*)(wsb + 146311168);  // 32768
    unsigned short* Wt2 = (unsigned short*)(wsb + 146343936);  // 32768

    k_init   <<<N_NODES / 256, 256, 0, stream>>>(dinv, count, mapping, pw, normPw);
    k_wprep  <<<64, 256, 0, stream>>>(Wc, Wt0, Wt1, Wt2);
    k_deg    <<<N_EDGES / 256, 256, 0, stream>>>(colp, ew, dinv, count);
    k_scan1  <<<128, 1024, 0, stream>>>(count, offs, blockSums);
    k_scan2  <<<1, 64, 0, stream>>>(blockSums, offs);
    k_fixup  <<<N_NODES / 256, 256, 0, stream>>>(offs, count, dinv, blockSums);
    k_scatter<<<N_EDGES / 256, 256, 0, stream>>>(rowp, colp, ew, dinv, offs, count, ssrc, scoef);
    k_aggregate<<<(N_NODES * 32) / 256, 256, 0, stream>>>(x, dinv, offs, ssrc, scoef, agg);
    k_gemm   <<<N_NODES / 128, 256, 0, stream>>>(agg, Wt0, Wt1, Wt2, bias, pw, normPw, score);
    k_sortchunks<<<N_NODES / CHUNK, 1024, 0, stream>>>(score, keys);
    k_rank   <<<N_NODES / 256, 256, 0, stream>>>(score, keys, perm, mapping, out);
    k_gate   <<<(NB * KKEEP * 32) / 256, 256, 0, stream>>>(agg, score, perm, out);
    k_edges  <<<N_EDGES / 256, 256, 0, stream>>>(rowp, colp, ew, mapping, out);
}